// Round 15
// baseline (133.747 us; speedup 1.0000x reference)
//
#include <hip/hip_runtime.h>

namespace {

constexpr int NQ = 12;
constexpr int NL = 3;
constexpr int FEAT = 64;
constexpr float PI_F = 3.14159265358979323846f;

typedef float f2 __attribute__((ext_vector_type(2)));

// ============================ constexpr GF(2) toolkit ============================
constexpr int par12(unsigned x) { int p = 0; for (int i = 0; i < 12; ++i) p ^= (int)((x >> i) & 1u); return p; }
constexpr int lead12(unsigned x) { for (int k = 11; k >= 0; --k) if ((x >> k) & 1u) return k; return -1; }

struct Ech { unsigned v[16] = {}; int n = 0; };
constexpr unsigned ech_reduce(const Ech& E, unsigned x) {
  for (int i = 0; i < E.n; ++i) { int lb = lead12(E.v[i]); if (lb >= 0 && ((x >> lb) & 1u)) x ^= E.v[i]; }
  return x;
}
constexpr bool ech_add(Ech& E, unsigned x) {
  unsigned r = ech_reduce(E, x);
  if (!r) return false;
  int lb = lead12(r);
  int pos = E.n;
  for (int i = 0; i < E.n; ++i) { if (lead12(E.v[i]) < lb) { pos = i; break; } }
  for (int i = E.n; i > pos; --i) E.v[i] = E.v[i - 1];
  E.v[pos] = r; E.n++;
  return true;
}

constexpr unsigned apmat(const unsigned* rows, unsigned v) {
  unsigned o = 0; for (int k = 0; k < 12; ++k) if (par12(rows[k] & v)) o |= 1u << k; return o;
}
constexpr bool inv12(const unsigned* in, unsigned* out) {
  unsigned a[12] = {}, b[12] = {};
  for (int k = 0; k < 12; ++k) { a[k] = in[k]; b[k] = 1u << k; }
  for (int c = 0; c < 12; ++c) {
    int p = -1;
    for (int r = c; r < 12; ++r) if ((a[r] >> c) & 1u) { p = r; break; }
    if (p < 0) return false;
    unsigned t = a[c]; a[c] = a[p]; a[p] = t; t = b[c]; b[c] = b[p]; b[p] = t;
    for (int r = 0; r < 12; ++r) if (r != c && ((a[r] >> c) & 1u)) { a[r] ^= a[c]; b[r] ^= b[c]; }
  }
  for (int k = 0; k < 12; ++k) out[k] = b[k];
  return true;
}
constexpr unsigned dropb(unsigned x, int t) {  // 11-bit: remove bit t of a 12-bit index
  unsigned lm = (1u << t) - 1u;
  return (x & lm) | ((x >> 1) & (0x7FFu & ~lm));
}
// 6-bit reg-index helpers: drop/insert pair bit c
constexpr int drop6(int r, int c) { int lm = (1 << c) - 1; return (r & lm) | ((r >> 1) & (31 & ~lm)); }
constexpr int ins6(int p, int slot, int c) { int lm = (1 << c) - 1; return (p & lm) | ((p & ~lm) << 1) | (slot << c); }

// ============ logical circuit tracking (deferred CNOT ring, verified r1-r14) ============
struct Logical {
  unsigned m[NL][NQ] = {}, rv[NL][NQ] = {}, rf[NQ] = {};
  bool ok = false;
};
constexpr Logical compute_raw() {
  Logical mp{};
  unsigned col[NQ] = {}, row[NQ] = {};
  for (int b = 0; b < NQ; ++b) { col[b] = 1u << b; row[b] = 1u << b; }
  mp.ok = true;
  for (int L = 0; L < NL; ++L) {
    for (int q = 0; q < NQ; ++q) {
      mp.m[L][q]  = col[NQ - 1 - q];
      mp.rv[L][q] = row[NQ - 1 - q];
      if (par12(mp.m[L][q] & mp.rv[L][q]) != 1) mp.ok = false;
    }
    for (int q = 0; q < NQ; ++q) {
      int bc = NQ - 1 - q;
      int bt = NQ - 1 - ((q + 1) % NQ);
      col[bc] ^= col[bt];
      row[bt] ^= row[bc];
    }
  }
  for (int q = 0; q < NQ; ++q) mp.rf[q] = row[NQ - 1 - q];
  return mp;
}

// ============================ phase/remap plan (VERIFIED r10-r14) ============================
struct Plan {
  unsigned l0m[NQ] = {}, l0r[NQ] = {};
  unsigned gm[4][6] = {};
  unsigned gr[4][6] = {};
  unsigned rf[NQ] = {};
  unsigned phi[4][6] = {};
  unsigned coffE[4][64] = {};
  int cb[4] = {};
  bool ok = false;
};

constexpr bool findH(const Ech& G, unsigned rho, unsigned& out) {
  for (unsigned t = 0; t < 12; ++t) {
    unsigned v = 1u << t;
    if (par12(v & rho) == 0 && ech_reduce(G, v)) { out = v; return true; }
  }
  for (unsigned v = 1; v < 4096u; ++v) {
    if (par12(v & rho) == 0 && ech_reduce(G, v)) { out = v; return true; }
  }
  return false;
}

constexpr Plan build_plan() {
  Logical raw = compute_raw();
  Plan P{};
  P.ok = raw.ok;
  for (int q = 0; q < NQ; ++q) { P.l0m[q] = raw.m[0][q]; P.l0r[q] = raw.rv[0][q]; }
  unsigned fwd[12] = {}, invc[12] = {};
  for (int k = 0; k < 12; ++k) { fwd[k] = 1u << k; invc[k] = 1u << k; }
  for (int ph = 0; ph < 4; ++ph) {
    const int L = 1 + ph / 2, q0 = (ph % 2) * 6;
    unsigned ml[6] = {};
    for (int i = 0; i < 6; ++i) ml[i] = raw.m[L][q0 + i];
    bool done = false;
    for (int cbi = 5; cbi >= 0 && !done; --cbi) {
      unsigned rho = fwd[6 + cbi];
      bool bad = false;
      int idx = -1;
      for (int i = 0; i < 6; ++i) if (par12(ml[i] & rho)) { idx = i; break; }
      unsigned uc = 0;
      Ech W{};
      if (idx >= 0) {
        uc = ml[idx];
        for (int i = 0; i < 6; ++i) {
          if (i == idx) continue;
          unsigned w = par12(ml[i] & rho) ? (ml[i] ^ uc) : ml[i];
          ech_add(W, w);
        }
        if (W.n > 5) bad = true;
      } else {
        for (int i = 0; i < 6; ++i) ech_add(W, ml[i]);
        if (W.n > 5) bad = true;
        if (!bad) {
          bool got = false;
          for (unsigned t = 0; t < 12 && !got; ++t) {
            unsigned v = 1u << t;
            if (par12(v & rho)) { uc = v; got = true; }
          }
          if (!got) bad = true;
        }
      }
      if (bad) continue;
      Ech G{};
      for (int i = 0; i < W.n && !bad; ++i) if (!ech_add(G, W.v[i])) bad = true;
      if (!bad && !ech_add(G, uc)) bad = true;
      if (bad) continue;
      unsigned regH[5] = {};
      int nH = W.n;
      for (int i = 0; i < nH; ++i) regH[i] = W.v[i];
      for (int slot = nH; slot < 5 && !bad; ++slot) {
        unsigned v = 0;
        if (!findH(G, rho, v)) { bad = true; break; }
        regH[slot] = v; ech_add(G, v);
      }
      if (bad) continue;
      unsigned lam[6] = {};
      for (int j = 0; j < 6 && !bad; ++j) {
        unsigned cand = invc[j];
        if (par12(cand & rho) != 0 || !ech_reduce(G, cand)) {
          if (!findH(G, rho, cand)) { bad = true; break; }
        }
        lam[j] = cand; ech_add(G, cand);
      }
      if (bad) continue;
      unsigned ncols[12] = {};
      for (int j = 0; j < 6; ++j) ncols[j] = lam[j];
      {
        int w = 0;
        for (int k = 0; k < 6; ++k) ncols[6 + k] = (k == cbi) ? uc : regH[w++];
      }
      unsigned Mrows[12] = {};
      for (int k = 0; k < 12; ++k) {
        unsigned r = 0;
        for (int j = 0; j < 12; ++j) r |= ((ncols[j] >> k) & 1u) << j;
        Mrows[k] = r;
      }
      unsigned fnew[12] = {};
      if (!inv12(Mrows, fnew)) continue;
      bool okp = true;
      unsigned gmv[6] = {}, grv[6] = {};
      for (int i = 0; i < 6 && okp; ++i) {
        unsigned SM = apmat(fnew, ml[i]);
        if (SM & 63u) okp = false;
        unsigned sg = 0;
        for (int k = 0; k < 12; ++k) if (par12(raw.rv[L][q0 + i] & ncols[k])) sg |= 1u << k;
        if (par12(SM & sg) != 1) okp = false;
        gmv[i] = SM; grv[i] = sg;
      }
      unsigned phj[6] = {}, Ust[6] = {};
      for (int j = 0; j < 6 && okp; ++j) {
        phj[j] = apmat(fwd, lam[j]);
        if ((phj[j] >> (6 + cbi)) & 1u) okp = false;
      }
      for (int k = 0; k < 6 && okp; ++k) {
        Ust[k] = apmat(fwd, ncols[6 + k]);
        if (((Ust[k] >> (6 + cbi)) & 1u) != (unsigned)(k == cbi ? 1 : 0)) okp = false;
      }
      if (!okp) continue;
      P.cb[ph] = cbi;
      for (int j = 0; j < 6; ++j) P.phi[ph][j] = phj[j];
      for (int rp = 0; rp < 64; ++rp) {
        unsigned psi = 0;
        for (int i = 0; i < 6; ++i) if ((rp >> i) & 1) psi ^= Ust[i];
        P.coffE[ph][rp] = dropb(psi, 6 + cbi);
      }
      for (int i = 0; i < 6; ++i) { P.gm[ph][i] = gmv[i]; P.gr[ph][i] = grv[i]; }
      for (int k = 0; k < 12; ++k) { fwd[k] = fnew[k]; invc[k] = ncols[k]; }
      done = true;
    }
    if (!done) { P.ok = false; return P; }
  }
  for (int q = 0; q < NQ; ++q) {
    unsigned sg = 0;
    for (int k = 0; k < 12; ++k) if (par12(raw.rf[q] & invc[k])) sg |= 1u << k;
    P.rf[q] = sg;
  }
  return P;
}

constexpr Plan PLAN = build_plan();
static_assert(PLAN.ok, "plan construction failed");

// per-phase SoA pair bit: != chunk bit of the preceding remap; minimize masks containing it
constexpr int pick_cp(int ph) {
  int best = -1, bestCost = 99;
  for (int c = 0; c < 6; ++c) {
    if (c == PLAN.cb[ph]) continue;
    int cost = 0;
    for (int i = 0; i < 6; ++i) if ((PLAN.gm[ph][i] >> (6 + c)) & 1u) ++cost;
    if (cost < bestCost) { bestCost = cost; best = c; }
  }
  return best;
}
constexpr int CPARR[4] = {pick_cp(0), pick_cp(1), pick_cp(2), pick_cp(3)};
static_assert(CPARR[0] != PLAN.cb[0] && CPARR[1] != PLAN.cb[1] &&
              CPARR[2] != PLAN.cb[2] && CPARR[3] != PLAN.cb[3], "cp==cb");

// ============================ vector helpers ============================
__device__ __forceinline__ f2 em(f2 a, f2 b, f2 c) { return __builtin_elementwise_fma(a, b, c); }
__device__ __forceinline__ f2 vswap(f2 a) { return __builtin_shufflevector(a, a, 1, 0); }
__device__ __forceinline__ f2 evens(f2 a, f2 b) { return __builtin_shufflevector(a, b, 0, 2); }
__device__ __forceinline__ f2 odds(f2 a, f2 b) { return __builtin_shufflevector(a, b, 1, 3); }

// AoS helpers for l0 (verified r14)
__device__ __forceinline__ f2 cmulv(f2 a, f2 urr, f2 uri) { return em(vswap(a), uri, a * urr); }

template<unsigned MLO>
__device__ __forceinline__ float shx(float v, int lane4) {
  if constexpr (MLO == 0u) {
    return v;
  } else if constexpr (MLO < 32u) {
    constexpr int off = (int)((MLO << 10) | 0x1fu);
    return __int_as_float(__builtin_amdgcn_ds_swizzle(__float_as_int(v), off));
  } else {
    int addr = lane4 ^ (int)(MLO << 2);
    return __int_as_float(__builtin_amdgcn_ds_bpermute(addr, __float_as_int(v)));
  }
}

// ---- l0 on sparse |0..0>, AoS (verified r14) ----
template<unsigned M, unsigned R>
__device__ __forceinline__ void l0_lane_gate(f2* st, float ghalf, float phihalf, int lane, int lane4) {
  float s, c, sf, cf;
  __sincosf(ghalf, &s, &c);
  __sincosf(phihalf, &sf, &cf);
  constexpr unsigned MLO = M & 63u;
  constexpr unsigned RLO = R & 63u;
  float sL = (__popc((int)(RLO & (unsigned)lane)) & 1) ? -1.f : 1.f;
  float ar = c * cf, aiS = (-c * sf) * sL, brS = (-s * cf) * sL, b0i = s * sf;
  f2 arr = {ar, ar};
  f2 aip = {-aiS, aiS};
  f2 brp = {brS, brS};
  f2 bii = {-b0i, b0i};
  f2 p;
  p.x = shx<MLO>(st[0].x, lane4);
  p.y = shx<MLO>(st[0].y, lane4);
  st[0] = em(vswap(p), bii, em(p, brp, em(vswap(st[0]), aip, st[0] * arr)));
}

template<int Q>
__device__ __forceinline__ void l0_lane(f2* st, const float* ang, const float* __restrict__ qp, int lane, int lane4) {
  if constexpr (Q < NQ) {
    constexpr unsigned M = PLAN.l0m[Q];
    if constexpr (M < 64u) {
      l0_lane_gate<M, PLAN.l0r[Q]>(st, 0.5f * (ang[Q] + qp[Q * 2 + 0]), 0.5f * qp[Q * 2 + 1], lane, lane4);
    }
    l0_lane<Q + 1>(st, ang, qp, lane, lane4);
  }
}
template<int Q, unsigned DONE>
__device__ __forceinline__ void l0_reg(f2* st, const float* ang, const float* __restrict__ qp) {
  if constexpr (Q < NQ) {
    constexpr unsigned M = PLAN.l0m[Q];
    if constexpr (M >= 64u) {
      constexpr unsigned TB = (M >> 6) & 63u;
      float sh = 0.5f * (ang[Q] + qp[Q * 2 + 0]);
      float ph = 0.5f * qp[Q * 2 + 1];
      float s, c, sf, cf;
      __sincosf(sh, &s, &c);
      __sincosf(ph, &sf, &cf);
      f2 u0r = {c * cf, c * cf};
      f2 u0i = {c * sf, -c * sf};
      f2 u1r = {s * cf, s * cf};
      f2 u1i = {-s * sf, s * sf};
      #pragma unroll
      for (int r = 0; r < 64; ++r) {
        if ((r & ~(int)DONE & 63) == 0) {
          f2 a = st[r];
          int r2 = r | (int)TB;
          st[r]  = cmulv(a, u0r, u0i);
          st[r2] = cmulv(a, u1r, u1i);
        }
      }
      l0_reg<Q + 1, DONE | TB>(st, ang, qp);
    } else {
      l0_reg<Q + 1, DONE>(st, ang, qp);
    }
  }
}

// ============================ SoA-pair gates ============================
// State: re[p] = {re(r0), re(r1)}, im[p] likewise; r = ins6(p, slot, C).
// Verified scalar semantics (r1-r14):
//   re' = ar*re - aiU*im + brU*pre - b0i*pim;  im' = ar*im + aiU*re + brU*pim + b0i*pre
// with aiU,brU sign-flipped by parity(reg & RH) and lane sign folded in.
// Slot parity folds into +-coefficient VECTORS -> zero swaps unless mask contains C.
template<unsigned M, unsigned R, int C, bool REAL>
__device__ __forceinline__ void gate_soa(f2* re, f2* im, float ghalf, float phihalf, int lane) {
  constexpr unsigned MH = (M >> 6) & 63u;
  constexpr unsigned RH = (R >> 6) & 63u;
  constexpr unsigned RL = R & 63u;
  constexpr bool SW = ((MH >> C) & 1u) != 0;
  constexpr unsigned mhp = (unsigned)drop6((int)(MH & ~(1u << C)), C);
  constexpr unsigned rhp = (unsigned)drop6((int)(RH & ~(1u << C)), C);
  constexpr unsigned rhc = (RH >> C) & 1u;
  float sL = (__popc((int)(RL & (unsigned)lane)) & 1) ? -1.f : 1.f;
  float s, c;
  __sincosf(ghalf, &s, &c);
  float ar, aiS, brS, b0i;
  if constexpr (REAL) {
    ar = c; aiS = 0.f; brS = -s * sL; b0i = 0.f;
  } else {
    float sf, cf;
    __sincosf(phihalf, &sf, &cf);
    ar = c * cf; aiS = (-c * sf) * sL; brS = (-s * cf) * sL; b0i = s * sf;
  }
  const f2 arr = {ar, ar};
  const f2 aiP = {aiS, rhc ? -aiS : aiS};
  const f2 aiM = -aiP;
  const f2 brP = {brS, rhc ? -brS : brS};
  const f2 brM = -brP;
  const f2 biN = {-b0i, -b0i};
  const f2 biP = {b0i, b0i};

  auto upd2 = [&](f2 are, f2 aim, f2 pre, f2 pim, bool rp, f2& ore, f2& oim) {
    const f2 aiV = rp ? aiM : aiP;
    const f2 brV = rp ? brM : brP;
    if constexpr (REAL) {
      ore = em(pre, brV, are * arr);
      oim = em(pim, brV, aim * arr);
    } else {
      ore = em(pre, brV, em(pim, biN, em(aim, -aiV, are * arr)));
      oim = em(pim, brV, em(pre, biP, em(are, aiV, aim * arr)));
    }
  };

  if constexpr (mhp == 0u) {
    static_assert(SW, "empty mask");
    #pragma unroll
    for (int p = 0; p < 32; ++p) {
      const bool rp = ((__builtin_popcount((unsigned)p & rhp)) & 1) != 0;
      f2 are = re[p], aim = im[p];
      f2 nre, nim;
      upd2(are, aim, vswap(are), vswap(aim), rp, nre, nim);
      re[p] = nre; im[p] = nim;
    }
  } else {
    constexpr unsigned TBp = mhp & (~mhp + 1u);
    #pragma unroll
    for (int p = 0; p < 32; ++p) {
      if ((p & (int)TBp) == 0) {
        const int p2 = p ^ (int)mhp;
        const bool rpA = ((__builtin_popcount((unsigned)p  & rhp)) & 1) != 0;
        const bool rpB = ((__builtin_popcount((unsigned)p2 & rhp)) & 1) != 0;
        f2 are = re[p],  aim = im[p];
        f2 bre = re[p2], bim = im[p2];
        f2 pa_re = SW ? vswap(bre) : bre;
        f2 pa_im = SW ? vswap(bim) : bim;
        f2 pb_re = SW ? vswap(are) : are;
        f2 pb_im = SW ? vswap(aim) : aim;
        f2 nre, nim;
        upd2(are, aim, pa_re, pa_im, rpA, nre, nim);
        re[p] = nre; im[p] = nim;
        upd2(bre, bim, pb_re, pb_im, rpB, nre, nim);
        re[p2] = nre; im[p2] = nim;
      }
    }
  }
}

template<int PH, int I>
__device__ __forceinline__ void do_phase_soa(f2* re, f2* im, const float* ang, const float* __restrict__ qp, int lane) {
  if constexpr (I < 6) {
    constexpr int L = 1 + PH / 2;
    constexpr bool REAL = (L == NL - 1);
    constexpr int q = (PH % 2) * 6 + I;
    float th0 = qp[(L * NQ + q) * 2 + 0];
    float ph1 = REAL ? 0.f : 0.5f * qp[(L * NQ + q) * 2 + 1];
    gate_soa<PLAN.gm[PH][I], PLAN.gr[PH][I], CPARR[PH], REAL>(re, im, 0.5f * (ang[q] + th0), ph1, lane);
    do_phase_soa<PH, I + 1>(re, im, ang, qp, lane);
  }
}

// ============================ remaps (verified addressing, r10-r14) ============================
__device__ __forceinline__ int pad(int a) { return a + (a >> 5); }

template<int PH>
__device__ __forceinline__ unsigned remap_base(int lane) {
  constexpr int b = PLAN.cb[PH];
  constexpr unsigned LM = (1u << (6 + b)) - 1u;
  unsigned B = 0;
  #pragma unroll
  for (int j = 0; j < 6; ++j) B ^= (unsigned)(-(int)((lane >> j) & 1)) & PLAN.phi[PH][j];
  return (B & LM) | ((B >> 1) & (0x7FFu & ~LM));
}

// first remap: AoS stA in, SoA(CPARR[0]) out
__device__ __forceinline__ void remap_first(const f2* stA, f2* re, f2* im, f2* lds, int lane) {
  constexpr int PH = 0;
  constexpr int b = PLAN.cb[PH];
  constexpr int C = CPARR[PH];
  constexpr int CBP = (b > C) ? b - 1 : b;   // chunk bit position in p-space
  constexpr unsigned LM6 = (1u << b) - 1u;
  unsigned rBe = remap_base<PH>(lane);
  #pragma unroll
  for (int s = 0; s < 2; ++s) {
    #pragma unroll
    for (int r = 0; r < 64; ++r) {
      if (((r >> b) & 1) == s) {
        const int cr = (r & (int)LM6) | ((r >> 1) & (31 & ~(int)LM6));
        lds[pad((cr << 6) | lane)] = stA[r];
      }
    }
    asm volatile("s_waitcnt lgkmcnt(0)" ::: "memory");
    #pragma unroll
    for (int p = 0; p < 32; ++p) {
      if (((p >> CBP) & 1) == s) {
        const int r0 = ins6(p, 0, C);
        const int r1 = ins6(p, 1, C);
        f2 A = lds[pad((int)(rBe ^ PLAN.coffE[PH][r0]))];
        f2 B = lds[pad((int)(rBe ^ PLAN.coffE[PH][r1]))];
        re[p] = evens(A, B);
        im[p] = odds(A, B);
      }
    }
    asm volatile("s_waitcnt lgkmcnt(0)" ::: "memory");
  }
}

// mid remaps: SoA(CPREV) in, SoA(CPARR[PH]) out
template<int PH>
__device__ __forceinline__ void remap_mid(f2* re, f2* im, f2* lds, int lane) {
  constexpr int b = PLAN.cb[PH];
  constexpr int CPREV = CPARR[PH - 1];
  constexpr int C = CPARR[PH];
  constexpr int CBP = (b > C) ? b - 1 : b;
  constexpr unsigned LM6 = (1u << b) - 1u;
  unsigned rBe = remap_base<PH>(lane);
  #pragma unroll
  for (int s = 0; s < 2; ++s) {
    #pragma unroll
    for (int r = 0; r < 64; ++r) {
      if (((r >> b) & 1) == s) {
        const int p = drop6(r, CPREV);
        const int slot = (r >> CPREV) & 1;
        const int cr = (r & (int)LM6) | ((r >> 1) & (31 & ~(int)LM6));
        f2 v = slot ? odds(re[p], im[p]) : evens(re[p], im[p]);
        lds[pad((cr << 6) | lane)] = v;
      }
    }
    asm volatile("s_waitcnt lgkmcnt(0)" ::: "memory");
    #pragma unroll
    for (int p = 0; p < 32; ++p) {
      if (((p >> CBP) & 1) == s) {
        const int r0 = ins6(p, 0, C);
        const int r1 = ins6(p, 1, C);
        f2 A = lds[pad((int)(rBe ^ PLAN.coffE[PH][r0]))];
        f2 B = lds[pad((int)(rBe ^ PLAN.coffE[PH][r1]))];
        re[p] = evens(A, B);
        im[p] = odds(A, B);
      }
    }
    asm volatile("s_waitcnt lgkmcnt(0)" ::: "memory");
  }
}

// NOTE: mid remap reads the NEW pair (r0,r1) differing in bit C != cb[PH], so both land in
// the same chunk stage; writes extract single slots, no pairing constraint. The OLD SoA
// registers being overwritten in stage s are exactly those read in stage s (chunk invariant
// holds in p-space: bit CBP of p == bit b of both r0,r1). Old-repr reads in the write stage
// use re/im[p(CPREV)] which may belong to either chunk -- but those values were fully
// written back in the PREVIOUS phase; within this remap, stage s only overwrites re/im[p]
// with bit CBP==s, and only reads (in write stage) regs r with bit b==s whose p(CPREV,...)
// hmm: p(CPREV) of r with bit b==s: bit b of r maps to some bit of p; r's bit b == s, so
// the source pairs read in stage s have that p-bit == s under CPREV-dropping IF b != CPREV.
// b == CPREV would split; guard below.
static_assert(PLAN.cb[1] != CPARR[0] || true, "");  // see runtime guard via static_assert below
static_assert(CPARR[0] != PLAN.cb[1] ? true : (PLAN.cb[1] == PLAN.cb[1]), "");

// hard guarantee: for each mid remap PH, cb[PH] != CPARR[PH-1] must hold so that the
// write-stage sources live in the same chunk being overwritten by the read stage.
static_assert(PLAN.cb[1] != CPARR[0], "cb[1]==cp[0]: write/read chunk alias");
static_assert(PLAN.cb[2] != CPARR[1], "cb[2]==cp[1]: write/read chunk alias");
static_assert(PLAN.cb[3] != CPARR[2], "cb[3]==cp[2]: write/read chunk alias");

__device__ __forceinline__ float redsum(float v, int lane4) {
  v += shx<1>(v, lane4);
  v += shx<2>(v, lane4);
  v += shx<4>(v, lane4);
  v += shx<8>(v, lane4);
  v += shx<16>(v, lane4);
  v += shx<32>(v, lane4);
  return v;
}
__device__ __forceinline__ float fast_tanh(float x) {
  float e = __expf(2.f * x);
  float r = __builtin_amdgcn_rcpf(e + 1.f);
  return 1.f - 2.f * r;
}

template<int Q>
__device__ __forceinline__ void finish(const float* af, float& outv, int lane, int lane4) {
  if constexpr (Q < NQ) {
    constexpr unsigned RLO = PLAN.rf[Q] & 63u;
    float a = af[Q];
    float sLn = (__popc((int)(RLO & (unsigned)lane)) & 1) ? -a : a;
    float t = redsum(sLn, lane4);
    if (lane == Q) outv = t;
    finish<Q + 1>(af, outv, lane, lane4);
  }
}

__global__ __launch_bounds__(64, 2) void qtr_kernel(const float* __restrict__ x,
                                                    const float* __restrict__ W,
                                                    const float* __restrict__ qp,
                                                    float* __restrict__ out) {
  __shared__ f2 ldsb[2112];  // 16.5KB (2048 + 64 pad slots)
  int b = blockIdx.x;
  int lane = threadIdx.x;
  int lane4 = lane << 2;

  // angles[q] = pi * tanh(dot(x[b], W[q]))
  float xv = x[b * FEAT + lane];
  float ang[NQ];
  #pragma unroll
  for (int q = 0; q < NQ; ++q) {
    float prod = redsum(xv * W[q * FEAT + lane], lane4);
    ang[q] = PI_F * fast_tanh(prod);
  }

  f2 re[32], im[32];
  {
    // sparse |0..0> + layer 0 in AoS (verified), then convert via remap_first
    f2 stA[64];
    stA[0].x = (lane == 0) ? 1.f : 0.f;
    stA[0].y = 0.f;
    l0_lane<0>(stA, ang, qp, lane, lane4);
    l0_reg<0, 0u>(stA, ang, qp);
    remap_first(stA, re, im, ldsb, lane);
  }
  do_phase_soa<0, 0>(re, im, ang, qp, lane);
  remap_mid<1>(re, im, ldsb, lane);
  do_phase_soa<1, 0>(re, im, ang, qp, lane);
  remap_mid<2>(re, im, ldsb, lane);
  do_phase_soa<2, 0>(re, im, ang, qp, lane);
  remap_mid<3>(re, im, ldsb, lane);
  do_phase_soa<3, 0>(re, im, ang, qp, lane);

  // probabilities -> 12 slotwise parity-signed accumulators (SoA CPARR[3])
  constexpr int C3 = CPARR[3];
  f2 accq[NQ];
  #pragma unroll
  for (int q = 0; q < NQ; ++q) { accq[q].x = 0.f; accq[q].y = 0.f; }
  #pragma unroll
  for (int p = 0; p < 32; ++p) {
    f2 pr2 = em(im[p], im[p], re[p] * re[p]);
    #pragma unroll
    for (int q = 0; q < NQ; ++q) {
      constexpr unsigned RFH_ALL[NQ] = {
        (PLAN.rf[0] >> 6) & 63u, (PLAN.rf[1] >> 6) & 63u, (PLAN.rf[2] >> 6) & 63u,
        (PLAN.rf[3] >> 6) & 63u, (PLAN.rf[4] >> 6) & 63u, (PLAN.rf[5] >> 6) & 63u,
        (PLAN.rf[6] >> 6) & 63u, (PLAN.rf[7] >> 6) & 63u, (PLAN.rf[8] >> 6) & 63u,
        (PLAN.rf[9] >> 6) & 63u, (PLAN.rf[10] >> 6) & 63u, (PLAN.rf[11] >> 6) & 63u};
      const unsigned rfh = RFH_ALL[q];
      const unsigned rfp = (unsigned)drop6((int)(rfh & ~(1u << C3)), C3);
      const unsigned rfc = (rfh >> C3) & 1u;
      const bool s0 = ((__builtin_popcount((unsigned)p & rfp)) & 1) != 0;
      const bool s1 = s0 ^ (rfc != 0);
      f2 sg; sg.x = s0 ? -1.f : 1.f; sg.y = s1 ? -1.f : 1.f;
      accq[q] = em(pr2, sg, accq[q]);
    }
  }
  float af[NQ];
  #pragma unroll
  for (int q = 0; q < NQ; ++q) af[q] = accq[q].x + accq[q].y;

  float outv = 0.f;
  finish<0>(af, outv, lane, lane4);

  if (lane < NQ) out[b * NQ + lane] = outv;
}

}  // namespace

extern "C" void kernel_launch(void* const* d_in, const int* in_sizes, int n_in,
                              void* d_out, int out_size, void* d_ws, size_t ws_size,
                              hipStream_t stream) {
  const float* x  = (const float*)d_in[0];
  const float* W  = (const float*)d_in[1];
  const float* qp = (const float*)d_in[2];
  float* out = (float*)d_out;
  qtr_kernel<<<8192, 64, 0, stream>>>(x, W, qp, out);
}